// Round 12
// baseline (323.478 us; speedup 1.0000x reference)
//
#include <hip/hip_runtime.h>
#include <hip/hip_fp16.h>
#include <cstdint>
#include <cstddef>

// Problem constants (from reference): N=100000, F_IN=64, F1=128, F2=64,
// E=3200000, NUM_GRAPHS=1024. N and E derived from in_sizes at launch.
#define NGRAPH 1024
#define CHUNK 8192       // edges per block in scatter pass (391 blocks @ E=3.2M)
#define SCTHREADS 512
#define SCIT (CHUNK / SCTHREADS)   // 16 edges per thread
#define MAXB 512         // max buckets (supports N <= 131072; here B=391)
#define CAP 16384        // padded bucket capacity (expected ~8192 edges/bucket)

typedef _Float16 f16x8 __attribute__((ext_vector_type(8)));
typedef float f32x4 __attribute__((ext_vector_type(4)));

// ================= one-pass padded-bucket CSR build =================
// bucket b = dst >> 8. Edge word packs (dst & 255) << 24 | src (src < 2^24).
// Bucket b owns ebuck/esrc slots [b*CAP, b*CAP + bcnt[b]).
// Block-local LDS counting sort -> coalesced global writes (full-line runs).

__global__ __launch_bounds__(SCTHREADS) void scatter1_kernel(const int* __restrict__ src,
        const int* __restrict__ dst, int E, int B,
        int* __restrict__ bcnt, unsigned* __restrict__ ebuck) {
    __shared__ unsigned sorted[CHUNK];      // 32 KB
    __shared__ int h[MAXB];                 // histogram / scan buffer
    __shared__ int lo[MAXB];                // exclusive local offsets
    __shared__ int cur[MAXB];               // LDS scatter cursors
    __shared__ int gbase[MAXB];             // reserved global base per bucket
    int blk = blockIdx.x, tid = threadIdx.x;
    int base = blk * CHUNK;
    int cnt_i = E - base; if (cnt_i > CHUNK) cnt_i = CHUNK;

    h[tid] = 0;
    __syncthreads();

    // load edges to registers + LDS histogram
    unsigned rd[SCIT], rs[SCIT];
    #pragma unroll
    for (int it = 0; it < SCIT; ++it) {
        int i = base + tid + it * SCTHREADS;
        if (i < E) {
            rd[it] = (unsigned)dst[i];
            rs[it] = (unsigned)src[i];
            atomicAdd(&h[rd[it] >> 8], 1);
        } else rd[it] = 0xFFFFFFFFu;
    }
    __syncthreads();

    // reserve global range for this block's share of each bucket
    int hv = h[tid];
    if (tid < B) gbase[tid] = hv ? atomicAdd(&bcnt[tid], hv) : 0;

    // exclusive scan of h over 512 entries (Hillis-Steele, in place)
    for (int o = 1; o < SCTHREADS; o <<= 1) {
        int t = (tid >= o) ? h[tid - o] : 0;
        __syncthreads();
        h[tid] += t;
        __syncthreads();
    }
    int excl = h[tid] - hv;
    lo[tid] = excl;
    cur[tid] = excl;
    __syncthreads();

    // scatter into LDS in bucket-sorted order
    #pragma unroll
    for (int it = 0; it < SCIT; ++it) {
        if (rd[it] != 0xFFFFFFFFu) {
            int b = rd[it] >> 8;
            int p = atomicAdd(&cur[b], 1);
            sorted[p] = ((rd[it] & 255u) << 24) | rs[it];
        }
    }
    __syncthreads();

    // coalesced copy-out: consecutive j -> consecutive global slots per bucket run
    for (int j = tid; j < cnt_i; j += SCTHREADS) {
        int l = 0, r = B - 1;                 // largest b with lo[b] <= j
        while (l < r) {
            int m = (l + r + 1) >> 1;
            if (lo[m] <= j) l = m; else r = m - 1;
        }
        ebuck[(size_t)l * CAP + gbase[l] + (j - lo[l])] = sorted[j];
    }
}

// Pass 2 (+fused pack): one block per bucket. LDS histogram -> deg/dinv/row_beg/
// row_end, LDS-cursor scatter of src into esrc (padded region), AND
// xs_h[n][f] = half(x[n][f]*dinv[n]) for the bucket's 256 nodes.
__global__ __launch_bounds__(256) void fine_kernel(const unsigned* __restrict__ ebuck,
        const int* __restrict__ bcnt, const float* __restrict__ x, int N, int B,
        int* __restrict__ row_beg, int* __restrict__ row_end, float* __restrict__ dinv,
        int* __restrict__ esrc, __half* __restrict__ xs) {
    __shared__ int hcnt[256];
    __shared__ int sc[256];
    __shared__ int loff[256];
    __shared__ float sdinv[256];
    int b = blockIdx.x, tid = threadIdx.x;
    int beg = b * CAP;
    int cnt = bcnt[b];
    hcnt[tid] = 0;
    __syncthreads();
    for (int e = tid; e < cnt; e += 256)
        atomicAdd(&hcnt[ebuck[beg + e] >> 24], 1);
    __syncthreads();
    int v = hcnt[tid];
    sc[tid] = v; __syncthreads();
    for (int o = 1; o < 256; o <<= 1) {
        int t = (tid >= o) ? sc[tid - o] : 0;
        __syncthreads();
        sc[tid] += t;
        __syncthreads();
    }
    int excl = sc[tid] - v;
    int n = (b << 8) + tid;
    float d = rsqrtf((float)(v + 1));   // +1 self loop
    if (n < N) {
        row_beg[n] = beg + excl;
        row_end[n] = beg + excl + v;
        dinv[n] = d;
    }
    loff[tid] = excl;
    sdinv[tid] = d;
    __syncthreads();
    for (int e = tid; e < cnt; e += 256) {
        unsigned u = ebuck[beg + e];
        int p = atomicAdd(&loff[u >> 24], 1);
        esrc[beg + p] = (int)(u & 0xFFFFFF);
    }
    // fused pack for this bucket's nodes
    const float4* xr = (const float4*)x;
    #pragma unroll
    for (int it = 0; it < 16; ++it) {
        int j = tid + it * 256;               // 0..4095
        int node = j >> 4, cc = j & 15;
        int gn = (b << 8) + node;
        if (gn < N) {
            float dd = sdinv[node];
            float4 vv = xr[(size_t)gn * 16 + cc];
            __half2 h0 = __floats2half2_rn(vv.x * dd, vv.y * dd);
            __half2 h1 = __floats2half2_rn(vv.z * dd, vv.w * dd);
            uint2 u;
            u.x = *(unsigned*)&h0;
            u.y = *(unsigned*)&h1;
            ((uint2*)xs)[(size_t)gn * 16 + cc] = u;
        }
    }
}

// ======== prep: block 0 = weight swizzle; blocks 1+ = goff binary search + bcnt 0
// W1s slot s = ((ks*8+nt)*4+q)*16+n  -> 8 halfs W1[ks*32+q*8+j][nt*16+n]
// W2s slot s = ((ks2*4+n2)*4+q)*16+n -> 8 halfs W2[ks2*32+q*8+j][n2*16+n]
__global__ __launch_bounds__(256) void prep_kernel(const float* __restrict__ W1,
        const float* __restrict__ W2, __half* __restrict__ W1s, __half* __restrict__ W2s,
        const int* __restrict__ batch, int N, int* __restrict__ goff,
        int* __restrict__ bcnt) {
    int t = threadIdx.x;
    if (blockIdx.x == 0) {
        #pragma unroll
        for (int it = 0; it < 4; ++it) {
            int s = t + it * 256;
            int n = s & 15, q = (s >> 4) & 3, nt = (s >> 6) & 7, ks = s >> 9;
            int k0 = ks * 32 + q * 8, col = nt * 16 + n;
            __align__(16) __half h[8];
            #pragma unroll
            for (int j = 0; j < 8; ++j) h[j] = (__half)W1[(k0 + j) * 128 + col];
            *((uint4*)&W1s[(size_t)s * 8]) = *(uint4*)h;
        }
        #pragma unroll
        for (int it = 0; it < 4; ++it) {
            int s = t + it * 256;
            int n = s & 15, q = (s >> 4) & 3, n2 = (s >> 6) & 3, ks2 = s >> 8;
            int k0 = ks2 * 32 + q * 8, col = n2 * 16 + n;
            __align__(16) __half h[8];
            #pragma unroll
            for (int j = 0; j < 8; ++j) h[j] = (__half)W2[(k0 + j) * 64 + col];
            *((uint4*)&W2s[(size_t)s * 8]) = *(uint4*)h;
        }
    } else {
        int g = (blockIdx.x - 1) * 256 + t;
        if (g < MAXB) bcnt[g] = 0;
        if (g > NGRAPH) return;
        if (g == NGRAPH) { goff[g] = N; return; }
        int lo = 0, hi = N;
        while (lo < hi) {
            int mid = (lo + hi) >> 1;
            if (batch[mid] < g) lo = mid + 1; else hi = mid;
        }
        goff[g] = lo;
    }
}

// ---------------- aggregation core (fp16 gather, packed fp16 partials) -------
// 64-lane wave per node: 8 groups x 8 lanes; group g owns every-8th edge.
// 4-deep unroll: with deg~33, one main-loop iteration covers the group's whole
// edge share -> 4 independent gathers in flight per lane (latency hiding).
__device__ inline void acc8h(__half2* a, const uint4& u) {
    const __half2* h = (const __half2*)&u;
    #pragma unroll
    for (int i = 0; i < 4; ++i) a[i] = __hadd2(a[i], h[i]);
}

// conv1 aggregate: fp16 output, no bias (feeds MFMA GEMM)
__global__ __launch_bounds__(256) void agg_h2h_kernel(const __half* __restrict__ xs,
        const int* __restrict__ esrc, const int* __restrict__ row_beg,
        const int* __restrict__ row_end, const float* __restrict__ dinv,
        __half* __restrict__ out, int N) {
    int n = blockIdx.x * 4 + (threadIdx.x >> 6);
    if (n >= N) return;
    int lane = threadIdx.x & 63;
    int g = lane >> 3, c = lane & 7;
    const uint4* xs4 = (const uint4*)xs;     // row stride 8 uint4
    int beg = row_beg[n], end = row_end[n];
    __half2 ha[4] = {}, hb[4] = {}, hc[4] = {}, hd[4] = {};
    if (g == 0) acc8h(ha, xs4[(size_t)n * 8 + c]);   // self loop
    int e = beg + g;
    for (; e + 24 < end; e += 32) {
        int s0 = esrc[e], s1 = esrc[e + 8], s2 = esrc[e + 16], s3 = esrc[e + 24];
        uint4 u0 = xs4[(size_t)s0 * 8 + c];
        uint4 u1 = xs4[(size_t)s1 * 8 + c];
        uint4 u2 = xs4[(size_t)s2 * 8 + c];
        uint4 u3 = xs4[(size_t)s3 * 8 + c];
        acc8h(ha, u0); acc8h(hb, u1); acc8h(hc, u2); acc8h(hd, u3);
    }
    for (; e < end; e += 8) acc8h(ha, xs4[(size_t)esrc[e] * 8 + c]);
    #pragma unroll
    for (int i = 0; i < 4; ++i) { ha[i] = __hadd2(ha[i], hb[i]); hc[i] = __hadd2(hc[i], hd[i]); }
    float a[8];
    #pragma unroll
    for (int i = 0; i < 4; ++i) {
        float2 fa = __half22float2(ha[i]), fb = __half22float2(hc[i]);
        a[2 * i]     = fa.x + fb.x;
        a[2 * i + 1] = fa.y + fb.y;
    }
    #pragma unroll
    for (int i = 0; i < 8; ++i) {
        a[i] += __shfl_xor(a[i], 8, 64);
        a[i] += __shfl_xor(a[i], 16, 64);
        a[i] += __shfl_xor(a[i], 32, 64);
    }
    if (g == 0) {
        float d = dinv[n];
        __align__(16) __half2 h[4];
        #pragma unroll
        for (int i = 0; i < 4; ++i)
            h[i] = __floats2half2_rn(a[2 * i] * d, a[2 * i + 1] * d);
        ((uint4*)out)[(size_t)n * 8 + c] = *(uint4*)h;
    }
}

// conv2 aggregate: fp32 output + bias (feeds readout)
__global__ __launch_bounds__(256) void agg_h2f_kernel(const __half* __restrict__ xs,
        const int* __restrict__ esrc, const int* __restrict__ row_beg,
        const int* __restrict__ row_end, const float* __restrict__ dinv,
        const float* __restrict__ bias, float* __restrict__ out, int N) {
    int n = blockIdx.x * 4 + (threadIdx.x >> 6);
    if (n >= N) return;
    int lane = threadIdx.x & 63;
    int g = lane >> 3, c = lane & 7;
    const uint4* xs4 = (const uint4*)xs;
    int beg = row_beg[n], end = row_end[n];
    __half2 ha[4] = {}, hb[4] = {}, hc[4] = {}, hd[4] = {};
    if (g == 0) acc8h(ha, xs4[(size_t)n * 8 + c]);
    int e = beg + g;
    for (; e + 24 < end; e += 32) {
        int s0 = esrc[e], s1 = esrc[e + 8], s2 = esrc[e + 16], s3 = esrc[e + 24];
        uint4 u0 = xs4[(size_t)s0 * 8 + c];
        uint4 u1 = xs4[(size_t)s1 * 8 + c];
        uint4 u2 = xs4[(size_t)s2 * 8 + c];
        uint4 u3 = xs4[(size_t)s3 * 8 + c];
        acc8h(ha, u0); acc8h(hb, u1); acc8h(hc, u2); acc8h(hd, u3);
    }
    for (; e < end; e += 8) acc8h(ha, xs4[(size_t)esrc[e] * 8 + c]);
    #pragma unroll
    for (int i = 0; i < 4; ++i) { ha[i] = __hadd2(ha[i], hb[i]); hc[i] = __hadd2(hc[i], hd[i]); }
    float a[8];
    #pragma unroll
    for (int i = 0; i < 4; ++i) {
        float2 fa = __half22float2(ha[i]), fb = __half22float2(hc[i]);
        a[2 * i]     = fa.x + fb.x;
        a[2 * i + 1] = fa.y + fb.y;
    }
    #pragma unroll
    for (int i = 0; i < 8; ++i) {
        a[i] += __shfl_xor(a[i], 8, 64);
        a[i] += __shfl_xor(a[i], 16, 64);
        a[i] += __shfl_xor(a[i], 32, 64);
    }
    if (g == 0) {
        float d = dinv[n];
        float4 bb0 = ((const float4*)bias)[c * 2];
        float4 bb1 = ((const float4*)bias)[c * 2 + 1];
        float4 o0, o1;
        o0.x = a[0] * d + bb0.x; o0.y = a[1] * d + bb0.y;
        o0.z = a[2] * d + bb0.z; o0.w = a[3] * d + bb0.w;
        o1.x = a[4] * d + bb1.x; o1.y = a[5] * d + bb1.y;
        o1.z = a[6] * d + bb1.z; o1.w = a[7] * d + bb1.w;
        ((float4*)out)[(size_t)n * 16 + c * 2] = o0;
        ((float4*)out)[(size_t)n * 16 + c * 2 + 1] = o1;
    }
}

// ---------------- fused MLP (MFMA fp16): ts = (relu(A@W1+b1) @ W2) * dinv ----
__global__ __launch_bounds__(256) void fusedmlp_kernel(const __half* __restrict__ A,
        const __half* __restrict__ W1s, const __half* __restrict__ W2s,
        const float* __restrict__ b1, const float* __restrict__ dinv,
        __half* __restrict__ T, int N) {
    __shared__ __align__(16) __half h1t[4][16][136];   // per-wave 16x128 tile, padded rows
    int tid = threadIdx.x;
    int w = tid >> 6, lane = tid & 63;
    int n15 = lane & 15, q = lane >> 4;
    int base = blockIdx.x * 64 + w * 16;

    int m = base + n15; if (m >= N) m = N - 1;          // clamp; stores guarded
    const uint4* Ar = (const uint4*)(A + (size_t)m * 64);
    uint4 ua0 = Ar[q];
    uint4 ua1 = Ar[4 + q];
    f16x8 a10 = *(f16x8*)&ua0;
    f16x8 a11 = *(f16x8*)&ua1;
    const uint4* W1f = (const uint4*)W1s;
    #pragma unroll
    for (int nt = 0; nt < 8; ++nt) {
        f32x4 c = {0.f, 0.f, 0.f, 0.f};
        uint4 ub0 = W1f[(nt * 4 + q) * 16 + n15];           // ks=0
        uint4 ub1 = W1f[((8 + nt) * 4 + q) * 16 + n15];     // ks=1
        c = __builtin_amdgcn_mfma_f32_16x16x32_f16(a10, *(f16x8*)&ub0, c, 0, 0, 0);
        c = __builtin_amdgcn_mfma_f32_16x16x32_f16(a11, *(f16x8*)&ub1, c, 0, 0, 0);
        float bv = b1[nt * 16 + n15];
        #pragma unroll
        for (int rr = 0; rr < 4; ++rr) {
            float hv = fmaxf(c[rr] + bv, 0.f);
            h1t[w][q * 4 + rr][nt * 16 + n15] = (__half)hv;  // row=node, col=feat
        }
    }
    __syncthreads();

    f16x8 a2[4];
    #pragma unroll
    for (int ks2 = 0; ks2 < 4; ++ks2)
        a2[ks2] = *(f16x8*)&h1t[w][n15][ks2 * 32 + q * 8];
    const uint4* W2f = (const uint4*)W2s;
    #pragma unroll
    for (int n2 = 0; n2 < 4; ++n2) {
        f32x4 c = {0.f, 0.f, 0.f, 0.f};
        #pragma unroll
        for (int ks2 = 0; ks2 < 4; ++ks2) {
            uint4 ub = W2f[((ks2 * 4 + n2) * 4 + q) * 16 + n15];
            c = __builtin_amdgcn_mfma_f32_16x16x32_f16(a2[ks2], *(f16x8*)&ub, c, 0, 0, 0);
        }
        #pragma unroll
        for (int rr = 0; rr < 4; ++rr) {
            int node = base + q * 4 + rr;
            if (node < N) {
                float v = c[rr] * dinv[node];
                T[(size_t)node * 64 + n2 * 16 + n15] = (__half)v;
            }
        }
    }
}

// ---------------- fused readout + head: out[g] = [mean|max](h2 rows) @ Wm + bm
__global__ __launch_bounds__(256) void readout_head_kernel(const float* __restrict__ h2,
        const int* __restrict__ goff, const float* __restrict__ Wm,
        const float* __restrict__ bm, float* __restrict__ out) {
    int g = blockIdx.x;
    int beg = goff[g], end = goff[g + 1];
    int f = threadIdx.x & 63;
    int c = threadIdx.x >> 6;
    float s = 0.f, m = -3.4e38f;
    for (int n = beg + c; n < end; n += 4) {
        float v = h2[(size_t)n * 64 + f];
        s += v;
        m = fmaxf(m, v);
    }
    __shared__ float ss[4][64], sm[4][64];
    __shared__ float rr[128];
    ss[c][f] = s; sm[c][f] = m;
    __syncthreads();
    if (c == 0) {
        float S = ss[0][f] + ss[1][f] + ss[2][f] + ss[3][f];
        float M = fmaxf(fmaxf(sm[0][f], sm[1][f]), fmaxf(sm[2][f], sm[3][f]));
        int cnt = end - beg;
        rr[f] = (cnt > 0) ? S / (float)cnt : 0.f;
        rr[64 + f] = (cnt > 0) ? M : 0.f;
    }
    __syncthreads();
    if (threadIdx.x < 64) {
        int j = threadIdx.x;
        float acc = bm[j];
        #pragma unroll 4
        for (int k = 0; k < 128; ++k)
            acc = fmaf(rr[k], Wm[k * 64 + j], acc);
        out[(size_t)g * 64 + j] = acc;
    }
}

extern "C" void kernel_launch(void* const* d_in, const int* in_sizes, int n_in,
                              void* d_out, int out_size, void* d_ws, size_t ws_size,
                              hipStream_t stream) {
    const float* x    = (const float*)d_in[0];
    const int*  adj   = (const int*)d_in[1];
    const int*  batch = (const int*)d_in[2];
    const float* W1   = (const float*)d_in[3];
    const float* b1   = (const float*)d_in[4];
    const float* W2   = (const float*)d_in[5];
    const float* b2   = (const float*)d_in[6];
    const float* Wm   = (const float*)d_in[7];
    const float* bm   = (const float*)d_in[8];
    float* out = (float*)d_out;

    const int N = in_sizes[0] / 64;
    const int E = in_sizes[1] / 2;
    const int* src = adj;
    const int* dst = adj + E;
    const int B = (N + 255) >> 8;                 // buckets (391)
    const int nblocks = (E + CHUNK - 1) / CHUNK;  // scatter blocks (391)

    // ---- workspace carve (256B aligned) ----
    char* w = (char*)d_ws;
    size_t off = 0;
    auto carve = [&](size_t bytes) -> void* {
        void* p = w + off;
        off += (bytes + 255) & ~(size_t)255;
        return p;
    };
    size_t halfbuf = (size_t)N * 64 * 2;
    float* dinv    = (float*)carve((size_t)N * 4);
    int*   row_beg = (int*)  carve((size_t)N * 4);
    int*   row_end = (int*)  carve((size_t)N * 4);
    int*   esrc    = (int*)  carve((size_t)B * CAP * 4);
    unsigned* ebuck= (unsigned*)carve((size_t)B * CAP * 4);
    int*   bcnt    = (int*)  carve((MAXB + 1) * 4);
    int*   goff    = (int*)  carve((NGRAPH + 1) * 4);
    __half* W1s    = (__half*)carve(8192 * 2);
    __half* W2s    = (__half*)carve(8192 * 2);
    __half* xs_h   = (__half*)carve(halfbuf);             // later reused as ts_h
    __half* agg1h  = (__half*)carve(halfbuf);
    float* h2      = (float*)carve((size_t)N * 64 * 4);
    __half* ts_h = xs_h;               // xs_h dead after first agg

    // prep: weight swizzle (block 0) + goff binary search + bcnt zero (blocks 1+)
    prep_kernel<<<1 + (NGRAPH + 256) / 256, 256, 0, stream>>>(W1, W2, W1s, W2s,
                                                              batch, N, goff, bcnt);

    // CSR build (one-pass padded bucket sort, LDS-sorted coalesced writes)
    scatter1_kernel<<<nblocks, SCTHREADS, 0, stream>>>(src, dst, E, B, bcnt, ebuck);
    fine_kernel<<<B, 256, 0, stream>>>(ebuck, bcnt, x, N, B, row_beg, row_end,
                                       dinv, esrc, xs_h);

    // conv1 aggregate: agg1h = half(dinv*(S+I)xs)
    agg_h2h_kernel<<<(N + 3) / 4, 256, 0, stream>>>(xs_h, esrc, row_beg, row_end,
                                                    dinv, agg1h, N);

    // fused MLP: ts_h = half((relu(agg1h@W1 + b1) @ W2) * dinv)
    fusedmlp_kernel<<<(N + 63) / 64, 256, 0, stream>>>(agg1h, W1s, W2s, b1, dinv, ts_h, N);

    // conv2 aggregate: h2 = dinv*(S+I)ts + b2
    agg_h2f_kernel<<<(N + 3) / 4, 256, 0, stream>>>(ts_h, esrc, row_beg, row_end,
                                                    dinv, b2, h2, N);

    // fused readout + head
    readout_head_kernel<<<NGRAPH, 256, 0, stream>>>(h2, goff, Wm, bm, out);
}

// Round 13
// 309.584 us; speedup vs baseline: 1.0449x; 1.0449x over previous
//
#include <hip/hip_runtime.h>
#include <hip/hip_fp16.h>
#include <cstdint>
#include <cstddef>

// Problem constants (from reference): N=100000, F_IN=64, F1=128, F2=64,
// E=3200000, NUM_GRAPHS=1024. N and E derived from in_sizes at launch.
#define NGRAPH 1024
#define CHUNK 8192       // edges per block in scatter pass (391 blocks @ E=3.2M)
#define SCTHREADS 512
#define SCIT (CHUNK / SCTHREADS)   // 16 edges per thread
#define MAXB 512         // max buckets (supports N <= 131072; here B=391)
#define CAP 16384        // padded bucket capacity (expected ~8192 edges/bucket)

typedef _Float16 f16x8 __attribute__((ext_vector_type(8)));
typedef float f32x4 __attribute__((ext_vector_type(4)));

// ================= one-pass padded-bucket CSR build =================
// bucket b = dst >> 8. Edge word packs (dst & 255) << 24 | src (src < 2^24).
// Bucket b owns ebuck/esrc slots [b*CAP, b*CAP + bcnt[b]).
// Block-local LDS counting sort -> coalesced global writes (full-line runs).

__global__ __launch_bounds__(SCTHREADS) void scatter1_kernel(const int* __restrict__ src,
        const int* __restrict__ dst, int E, int B,
        int* __restrict__ bcnt, unsigned* __restrict__ ebuck) {
    __shared__ unsigned sorted[CHUNK];      // 32 KB
    __shared__ int h[MAXB];                 // histogram / scan buffer
    __shared__ int lo[MAXB];                // exclusive local offsets
    __shared__ int cur[MAXB];               // LDS scatter cursors
    __shared__ int gbase[MAXB];             // reserved global base per bucket
    int blk = blockIdx.x, tid = threadIdx.x;
    int base = blk * CHUNK;
    int cnt_i = E - base; if (cnt_i > CHUNK) cnt_i = CHUNK;

    h[tid] = 0;
    __syncthreads();

    // load edges to registers + LDS histogram
    unsigned rd[SCIT], rs[SCIT];
    #pragma unroll
    for (int it = 0; it < SCIT; ++it) {
        int i = base + tid + it * SCTHREADS;
        if (i < E) {
            rd[it] = (unsigned)dst[i];
            rs[it] = (unsigned)src[i];
            atomicAdd(&h[rd[it] >> 8], 1);
        } else rd[it] = 0xFFFFFFFFu;
    }
    __syncthreads();

    // reserve global range for this block's share of each bucket
    int hv = h[tid];
    if (tid < B) gbase[tid] = hv ? atomicAdd(&bcnt[tid], hv) : 0;

    // exclusive scan of h over 512 entries (Hillis-Steele, in place)
    for (int o = 1; o < SCTHREADS; o <<= 1) {
        int t = (tid >= o) ? h[tid - o] : 0;
        __syncthreads();
        h[tid] += t;
        __syncthreads();
    }
    int excl = h[tid] - hv;
    lo[tid] = excl;
    cur[tid] = excl;
    __syncthreads();

    // scatter into LDS in bucket-sorted order
    #pragma unroll
    for (int it = 0; it < SCIT; ++it) {
        if (rd[it] != 0xFFFFFFFFu) {
            int b = rd[it] >> 8;
            int p = atomicAdd(&cur[b], 1);
            sorted[p] = ((rd[it] & 255u) << 24) | rs[it];
        }
    }
    __syncthreads();

    // coalesced copy-out: consecutive j -> consecutive global slots per bucket
    // run. Bucket lookup via proportional hint + local walk (runs ~21 edges,
    // drift ±4 buckets -> ~3-5 LDS reads vs 9-step binary search).
    for (int j = tid; j < cnt_i; j += SCTHREADS) {
        int l = (int)(((long long)j * B) / cnt_i);
        if (l > B - 1) l = B - 1;
        while (lo[l] > j) --l;
        while (l + 1 < B && lo[l + 1] <= j) ++l;
        ebuck[(size_t)l * CAP + gbase[l] + (j - lo[l])] = sorted[j];
    }
}

// Pass 2 (+fused pack): one block per bucket. LDS histogram -> deg/dinv/row_beg/
// row_end, LDS-cursor scatter of src into esrc (padded region), AND
// xs_h[n][f] = half(x[n][f]*dinv[n]) for the bucket's 256 nodes.
__global__ __launch_bounds__(256) void fine_kernel(const unsigned* __restrict__ ebuck,
        const int* __restrict__ bcnt, const float* __restrict__ x, int N, int B,
        int* __restrict__ row_beg, int* __restrict__ row_end, float* __restrict__ dinv,
        int* __restrict__ esrc, __half* __restrict__ xs) {
    __shared__ int hcnt[256];
    __shared__ int sc[256];
    __shared__ int loff[256];
    __shared__ float sdinv[256];
    int b = blockIdx.x, tid = threadIdx.x;
    int beg = b * CAP;
    int cnt = bcnt[b];
    hcnt[tid] = 0;
    __syncthreads();
    for (int e = tid; e < cnt; e += 256)
        atomicAdd(&hcnt[ebuck[beg + e] >> 24], 1);
    __syncthreads();
    int v = hcnt[tid];
    sc[tid] = v; __syncthreads();
    for (int o = 1; o < 256; o <<= 1) {
        int t = (tid >= o) ? sc[tid - o] : 0;
        __syncthreads();
        sc[tid] += t;
        __syncthreads();
    }
    int excl = sc[tid] - v;
    int n = (b << 8) + tid;
    float d = rsqrtf((float)(v + 1));   // +1 self loop
    if (n < N) {
        row_beg[n] = beg + excl;
        row_end[n] = beg + excl + v;
        dinv[n] = d;
    }
    loff[tid] = excl;
    sdinv[tid] = d;
    __syncthreads();
    for (int e = tid; e < cnt; e += 256) {
        unsigned u = ebuck[beg + e];
        int p = atomicAdd(&loff[u >> 24], 1);
        esrc[beg + p] = (int)(u & 0xFFFFFF);
    }
    // fused pack for this bucket's nodes
    const float4* xr = (const float4*)x;
    #pragma unroll
    for (int it = 0; it < 16; ++it) {
        int j = tid + it * 256;               // 0..4095
        int node = j >> 4, cc = j & 15;
        int gn = (b << 8) + node;
        if (gn < N) {
            float dd = sdinv[node];
            float4 vv = xr[(size_t)gn * 16 + cc];
            __half2 h0 = __floats2half2_rn(vv.x * dd, vv.y * dd);
            __half2 h1 = __floats2half2_rn(vv.z * dd, vv.w * dd);
            uint2 u;
            u.x = *(unsigned*)&h0;
            u.y = *(unsigned*)&h1;
            ((uint2*)xs)[(size_t)gn * 16 + cc] = u;
        }
    }
}

// ======== prep: block 0 = weight swizzle; blocks 1+ = goff binary search + bcnt 0
// W1s slot s = ((ks*8+nt)*4+q)*16+n  -> 8 halfs W1[ks*32+q*8+j][nt*16+n]
// W2s slot s = ((ks2*4+n2)*4+q)*16+n -> 8 halfs W2[ks2*32+q*8+j][n2*16+n]
__global__ __launch_bounds__(256) void prep_kernel(const float* __restrict__ W1,
        const float* __restrict__ W2, __half* __restrict__ W1s, __half* __restrict__ W2s,
        const int* __restrict__ batch, int N, int* __restrict__ goff,
        int* __restrict__ bcnt) {
    int t = threadIdx.x;
    if (blockIdx.x == 0) {
        #pragma unroll
        for (int it = 0; it < 4; ++it) {
            int s = t + it * 256;
            int n = s & 15, q = (s >> 4) & 3, nt = (s >> 6) & 7, ks = s >> 9;
            int k0 = ks * 32 + q * 8, col = nt * 16 + n;
            __align__(16) __half h[8];
            #pragma unroll
            for (int j = 0; j < 8; ++j) h[j] = (__half)W1[(k0 + j) * 128 + col];
            *((uint4*)&W1s[(size_t)s * 8]) = *(uint4*)h;
        }
        #pragma unroll
        for (int it = 0; it < 4; ++it) {
            int s = t + it * 256;
            int n = s & 15, q = (s >> 4) & 3, n2 = (s >> 6) & 3, ks2 = s >> 8;
            int k0 = ks2 * 32 + q * 8, col = n2 * 16 + n;
            __align__(16) __half h[8];
            #pragma unroll
            for (int j = 0; j < 8; ++j) h[j] = (__half)W2[(k0 + j) * 64 + col];
            *((uint4*)&W2s[(size_t)s * 8]) = *(uint4*)h;
        }
    } else {
        int g = (blockIdx.x - 1) * 256 + t;
        if (g < MAXB) bcnt[g] = 0;
        if (g > NGRAPH) return;
        if (g == NGRAPH) { goff[g] = N; return; }
        int lo = 0, hi = N;
        while (lo < hi) {
            int mid = (lo + hi) >> 1;
            if (batch[mid] < g) lo = mid + 1; else hi = mid;
        }
        goff[g] = lo;
    }
}

// ---------------- aggregation core (fp16 gather, packed fp16 partials) -------
// 64-lane wave per node: 8 groups x 8 lanes; group g owns every-8th edge.
// 2-deep unroll (measured best at deg~33: R11 59.2us; 4-deep regressed R12).
__device__ inline void acc8h(__half2* a, const uint4& u) {
    const __half2* h = (const __half2*)&u;
    #pragma unroll
    for (int i = 0; i < 4; ++i) a[i] = __hadd2(a[i], h[i]);
}

// conv1 aggregate: fp16 output, no bias (feeds MFMA GEMM)
__global__ __launch_bounds__(256) void agg_h2h_kernel(const __half* __restrict__ xs,
        const int* __restrict__ esrc, const int* __restrict__ row_beg,
        const int* __restrict__ row_end, const float* __restrict__ dinv,
        __half* __restrict__ out, int N) {
    int n = blockIdx.x * 4 + (threadIdx.x >> 6);
    if (n >= N) return;
    int lane = threadIdx.x & 63;
    int g = lane >> 3, c = lane & 7;
    const uint4* xs4 = (const uint4*)xs;     // row stride 8 uint4
    int beg = row_beg[n], end = row_end[n];
    __half2 ha[4] = {}, hb[4] = {};
    if (g == 0) acc8h(ha, xs4[(size_t)n * 8 + c]);   // self loop
    int e = beg + g;
    for (; e + 8 < end; e += 16) {
        int s0 = esrc[e], s1 = esrc[e + 8];
        uint4 u0 = xs4[(size_t)s0 * 8 + c];
        uint4 u1 = xs4[(size_t)s1 * 8 + c];
        acc8h(ha, u0);
        acc8h(hb, u1);
    }
    if (e < end) acc8h(ha, xs4[(size_t)esrc[e] * 8 + c]);
    float a[8];
    #pragma unroll
    for (int i = 0; i < 4; ++i) {
        float2 fa = __half22float2(ha[i]), fb = __half22float2(hb[i]);
        a[2 * i]     = fa.x + fb.x;
        a[2 * i + 1] = fa.y + fb.y;
    }
    #pragma unroll
    for (int i = 0; i < 8; ++i) {
        a[i] += __shfl_xor(a[i], 8, 64);
        a[i] += __shfl_xor(a[i], 16, 64);
        a[i] += __shfl_xor(a[i], 32, 64);
    }
    if (g == 0) {
        float d = dinv[n];
        __align__(16) __half2 h[4];
        #pragma unroll
        for (int i = 0; i < 4; ++i)
            h[i] = __floats2half2_rn(a[2 * i] * d, a[2 * i + 1] * d);
        ((uint4*)out)[(size_t)n * 8 + c] = *(uint4*)h;
    }
}

// conv2 aggregate: fp32 output + bias (feeds readout)
__global__ __launch_bounds__(256) void agg_h2f_kernel(const __half* __restrict__ xs,
        const int* __restrict__ esrc, const int* __restrict__ row_beg,
        const int* __restrict__ row_end, const float* __restrict__ dinv,
        const float* __restrict__ bias, float* __restrict__ out, int N) {
    int n = blockIdx.x * 4 + (threadIdx.x >> 6);
    if (n >= N) return;
    int lane = threadIdx.x & 63;
    int g = lane >> 3, c = lane & 7;
    const uint4* xs4 = (const uint4*)xs;
    int beg = row_beg[n], end = row_end[n];
    __half2 ha[4] = {}, hb[4] = {};
    if (g == 0) acc8h(ha, xs4[(size_t)n * 8 + c]);
    int e = beg + g;
    for (; e + 8 < end; e += 16) {
        int s0 = esrc[e], s1 = esrc[e + 8];
        uint4 u0 = xs4[(size_t)s0 * 8 + c];
        uint4 u1 = xs4[(size_t)s1 * 8 + c];
        acc8h(ha, u0);
        acc8h(hb, u1);
    }
    if (e < end) acc8h(ha, xs4[(size_t)esrc[e] * 8 + c]);
    float a[8];
    #pragma unroll
    for (int i = 0; i < 4; ++i) {
        float2 fa = __half22float2(ha[i]), fb = __half22float2(hb[i]);
        a[2 * i]     = fa.x + fb.x;
        a[2 * i + 1] = fa.y + fb.y;
    }
    #pragma unroll
    for (int i = 0; i < 8; ++i) {
        a[i] += __shfl_xor(a[i], 8, 64);
        a[i] += __shfl_xor(a[i], 16, 64);
        a[i] += __shfl_xor(a[i], 32, 64);
    }
    if (g == 0) {
        float d = dinv[n];
        float4 bb0 = ((const float4*)bias)[c * 2];
        float4 bb1 = ((const float4*)bias)[c * 2 + 1];
        float4 o0, o1;
        o0.x = a[0] * d + bb0.x; o0.y = a[1] * d + bb0.y;
        o0.z = a[2] * d + bb0.z; o0.w = a[3] * d + bb0.w;
        o1.x = a[4] * d + bb1.x; o1.y = a[5] * d + bb1.y;
        o1.z = a[6] * d + bb1.z; o1.w = a[7] * d + bb1.w;
        ((float4*)out)[(size_t)n * 16 + c * 2] = o0;
        ((float4*)out)[(size_t)n * 16 + c * 2 + 1] = o1;
    }
}

// ---------------- fused MLP (MFMA fp16): ts = (relu(A@W1+b1) @ W2) * dinv ----
__global__ __launch_bounds__(256) void fusedmlp_kernel(const __half* __restrict__ A,
        const __half* __restrict__ W1s, const __half* __restrict__ W2s,
        const float* __restrict__ b1, const float* __restrict__ dinv,
        __half* __restrict__ T, int N) {
    __shared__ __align__(16) __half h1t[4][16][136];   // per-wave 16x128 tile, padded rows
    int tid = threadIdx.x;
    int w = tid >> 6, lane = tid & 63;
    int n15 = lane & 15, q = lane >> 4;
    int base = blockIdx.x * 64 + w * 16;

    int m = base + n15; if (m >= N) m = N - 1;          // clamp; stores guarded
    const uint4* Ar = (const uint4*)(A + (size_t)m * 64);
    uint4 ua0 = Ar[q];
    uint4 ua1 = Ar[4 + q];
    f16x8 a10 = *(f16x8*)&ua0;
    f16x8 a11 = *(f16x8*)&ua1;
    const uint4* W1f = (const uint4*)W1s;
    #pragma unroll
    for (int nt = 0; nt < 8; ++nt) {
        f32x4 c = {0.f, 0.f, 0.f, 0.f};
        uint4 ub0 = W1f[(nt * 4 + q) * 16 + n15];           // ks=0
        uint4 ub1 = W1f[((8 + nt) * 4 + q) * 16 + n15];     // ks=1
        c = __builtin_amdgcn_mfma_f32_16x16x32_f16(a10, *(f16x8*)&ub0, c, 0, 0, 0);
        c = __builtin_amdgcn_mfma_f32_16x16x32_f16(a11, *(f16x8*)&ub1, c, 0, 0, 0);
        float bv = b1[nt * 16 + n15];
        #pragma unroll
        for (int rr = 0; rr < 4; ++rr) {
            float hv = fmaxf(c[rr] + bv, 0.f);
            h1t[w][q * 4 + rr][nt * 16 + n15] = (__half)hv;  // row=node, col=feat
        }
    }
    __syncthreads();

    f16x8 a2[4];
    #pragma unroll
    for (int ks2 = 0; ks2 < 4; ++ks2)
        a2[ks2] = *(f16x8*)&h1t[w][n15][ks2 * 32 + q * 8];
    const uint4* W2f = (const uint4*)W2s;
    #pragma unroll
    for (int n2 = 0; n2 < 4; ++n2) {
        f32x4 c = {0.f, 0.f, 0.f, 0.f};
        #pragma unroll
        for (int ks2 = 0; ks2 < 4; ++ks2) {
            uint4 ub = W2f[((ks2 * 4 + n2) * 4 + q) * 16 + n15];
            c = __builtin_amdgcn_mfma_f32_16x16x32_f16(a2[ks2], *(f16x8*)&ub, c, 0, 0, 0);
        }
        #pragma unroll
        for (int rr = 0; rr < 4; ++rr) {
            int node = base + q * 4 + rr;
            if (node < N) {
                float v = c[rr] * dinv[node];
                T[(size_t)node * 64 + n2 * 16 + n15] = (__half)v;
            }
        }
    }
}

// ---------------- fused readout + head: out[g] = [mean|max](h2 rows) @ Wm + bm
__global__ __launch_bounds__(256) void readout_head_kernel(const float* __restrict__ h2,
        const int* __restrict__ goff, const float* __restrict__ Wm,
        const float* __restrict__ bm, float* __restrict__ out) {
    int g = blockIdx.x;
    int beg = goff[g], end = goff[g + 1];
    int f = threadIdx.x & 63;
    int c = threadIdx.x >> 6;
    float s = 0.f, m = -3.4e38f;
    for (int n = beg + c; n < end; n += 4) {
        float v = h2[(size_t)n * 64 + f];
        s += v;
        m = fmaxf(m, v);
    }
    __shared__ float ss[4][64], sm[4][64];
    __shared__ float rr[128];
    ss[c][f] = s; sm[c][f] = m;
    __syncthreads();
    if (c == 0) {
        float S = ss[0][f] + ss[1][f] + ss[2][f] + ss[3][f];
        float M = fmaxf(fmaxf(sm[0][f], sm[1][f]), fmaxf(sm[2][f], sm[3][f]));
        int cnt = end - beg;
        rr[f] = (cnt > 0) ? S / (float)cnt : 0.f;
        rr[64 + f] = (cnt > 0) ? M : 0.f;
    }
    __syncthreads();
    if (threadIdx.x < 64) {
        int j = threadIdx.x;
        float acc = bm[j];
        #pragma unroll 4
        for (int k = 0; k < 128; ++k)
            acc = fmaf(rr[k], Wm[k * 64 + j], acc);
        out[(size_t)g * 64 + j] = acc;
    }
}

extern "C" void kernel_launch(void* const* d_in, const int* in_sizes, int n_in,
                              void* d_out, int out_size, void* d_ws, size_t ws_size,
                              hipStream_t stream) {
    const float* x    = (const float*)d_in[0];
    const int*  adj   = (const int*)d_in[1];
    const int*  batch = (const int*)d_in[2];
    const float* W1   = (const float*)d_in[3];
    const float* b1   = (const float*)d_in[4];
    const float* W2   = (const float*)d_in[5];
    const float* b2   = (const float*)d_in[6];
    const float* Wm   = (const float*)d_in[7];
    const float* bm   = (const float*)d_in[8];
    float* out = (float*)d_out;

    const int N = in_sizes[0] / 64;
    const int E = in_sizes[1] / 2;
    const int* src = adj;
    const int* dst = adj + E;
    const int B = (N + 255) >> 8;                 // buckets (391)
    const int nblocks = (E + CHUNK - 1) / CHUNK;  // scatter blocks (391)

    // ---- workspace carve (256B aligned) ----
    char* w = (char*)d_ws;
    size_t off = 0;
    auto carve = [&](size_t bytes) -> void* {
        void* p = w + off;
        off += (bytes + 255) & ~(size_t)255;
        return p;
    };
    size_t halfbuf = (size_t)N * 64 * 2;
    float* dinv    = (float*)carve((size_t)N * 4);
    int*   row_beg = (int*)  carve((size_t)N * 4);
    int*   row_end = (int*)  carve((size_t)N * 4);
    int*   esrc    = (int*)  carve((size_t)B * CAP * 4);
    unsigned* ebuck= (unsigned*)carve((size_t)B * CAP * 4);
    int*   bcnt    = (int*)  carve((MAXB + 1) * 4);
    int*   goff    = (int*)  carve((NGRAPH + 1) * 4);
    __half* W1s    = (__half*)carve(8192 * 2);
    __half* W2s    = (__half*)carve(8192 * 2);
    __half* xs_h   = (__half*)carve(halfbuf);             // later reused as ts_h
    __half* agg1h  = (__half*)carve(halfbuf);
    float* h2      = (float*)carve((size_t)N * 64 * 4);
    __half* ts_h = xs_h;               // xs_h dead after first agg

    // prep: weight swizzle (block 0) + goff binary search + bcnt zero (blocks 1+)
    prep_kernel<<<1 + (NGRAPH + 256) / 256, 256, 0, stream>>>(W1, W2, W1s, W2s,
                                                              batch, N, goff, bcnt);

    // CSR build (one-pass padded bucket sort, LDS-sorted coalesced writes)
    scatter1_kernel<<<nblocks, SCTHREADS, 0, stream>>>(src, dst, E, B, bcnt, ebuck);
    fine_kernel<<<B, 256, 0, stream>>>(ebuck, bcnt, x, N, B, row_beg, row_end,
                                       dinv, esrc, xs_h);

    // conv1 aggregate: agg1h = half(dinv*(S+I)xs)
    agg_h2h_kernel<<<(N + 3) / 4, 256, 0, stream>>>(xs_h, esrc, row_beg, row_end,
                                                    dinv, agg1h, N);

    // fused MLP: ts_h = half((relu(agg1h@W1 + b1) @ W2) * dinv)
    fusedmlp_kernel<<<(N + 63) / 64, 256, 0, stream>>>(agg1h, W1s, W2s, b1, dinv, ts_h, N);

    // conv2 aggregate: h2 = dinv*(S+I)ts + b2
    agg_h2f_kernel<<<(N + 3) / 4, 256, 0, stream>>>(ts_h, esrc, row_beg, row_end,
                                                    dinv, b2, h2, N);

    // fused readout + head
    readout_head_kernel<<<NGRAPH, 256, 0, stream>>>(h2, goff, Wm, bm, out);
}